// Round 11
// baseline (576.846 us; speedup 1.0000x reference)
//
#include <hip/hip_runtime.h>

// GNNRoIFusion on MI355X (gfx950).
// B=2, H=W=128, C=256, HEADS=4, D=64, M=3, P=32768 pixels.
// Round 18: attn_ln lane remap — lane e owns 16 CONTIGUOUS channels
// (head = e>>2). XLR/residual loads become 16B u16x8 (24 wide loads vs 48
// narrow); head-score reduction = 4-lane quad_perm DPP butterfly (2 hops vs
// rsum16's 4); xl kept raw-bf16 in regs, converted on use (abs() modifier
// free). Same fp32 math, reorganized lanes. gemm (r15), conv (r14/r17),
// chunking+XCD swizzle (r11) unchanged.

#define Pn 32768
#define PADR 16900  // 130*130 padded rows per batch

typedef __attribute__((ext_vector_type(8))) short bf16x8;
typedef __attribute__((ext_vector_type(4))) float f32x4;
typedef __attribute__((ext_vector_type(4))) unsigned short u16x4;
typedef __attribute__((ext_vector_type(8))) unsigned short u16x8;
typedef __attribute__((ext_vector_type(2))) unsigned int u32x2;

__device__ __forceinline__ float b2f(short s) {
  unsigned u = ((unsigned)(unsigned short)s) << 16;
  float f;
  __builtin_memcpy(&f, &u, 4);
  return f;
}
__device__ __forceinline__ float asf(unsigned u) {
  float f;
  __builtin_memcpy(&f, &u, 4);
  return f;
}
__device__ __forceinline__ short f2b(float f) {
  unsigned u;
  __builtin_memcpy(&u, &f, 4);
  u += 0x7fffu + ((u >> 16) & 1u);   // RNE to bf16
  return (short)(u >> 16);
}
__device__ __forceinline__ float ldany(const void* p, int i, int bf) {
  return bf ? b2f(((const short*)p)[i]) : ((const float*)p)[i];
}
// async global->LDS, 16B per lane; lds base wave-uniform, lane i -> base+16i
__device__ __forceinline__ void gload_lds16(const short* g, short* l) {
  __builtin_amdgcn_global_load_lds(
      (const __attribute__((address_space(1))) unsigned int*)g,
      (__attribute__((address_space(3))) unsigned int*)l, 16, 0, 0);
}

// Bijective XCD-chunk swizzle (m204): hardware round-robins linear block id
// across 8 XCDs; remap so each XCD owns a contiguous chunk of work ids.
__device__ __forceinline__ int xcd_swz(int bid, int nwg) {
  int q = nwg >> 3, r = nwg & 7;
  int x = bid & 7, p = bid >> 3;
  return (x < r ? x * (q + 1) : r * (q + 1) + (x - r) * q) + p;
}

// DPP add helpers (VALU pipe, no LDS).
template <int CTRL>
__device__ __forceinline__ float dpp_add(float v) {
  int s;
  __builtin_memcpy(&s, &v, 4);
  int m = __builtin_amdgcn_update_dpp(0, s, CTRL, 0xF, 0xF, false);
  float f;
  __builtin_memcpy(&f, &m, 4);
  return v + f;
}
__device__ __forceinline__ float rsum16(float v) {  // sum over 16-lane row
  v = dpp_add<0x121>(v);   // row_ror:1
  v = dpp_add<0x122>(v);   // row_ror:2
  v = dpp_add<0x124>(v);   // row_ror:4
  v = dpp_add<0x128>(v);   // row_ror:8
  return v;
}
__device__ __forceinline__ float rsum4(float v) {   // sum over 4-lane quad
  v = dpp_add<0xB1>(v);    // quad_perm [1,0,3,2]
  v = dpp_add<0x4E>(v);    // quad_perm [2,3,0,1]
  return v;
}

// ---------- dtype probe ------------------------------------------------------
__global__ __launch_bounds__(256) void detect_dtype(const void* probe, int* flag) {
  const short* s = (const short*)probe;
  int cnt = 0;
#pragma unroll
  for (int i = 0; i < 8; ++i) {
    short v = s[(threadIdx.x * 8 + i) * 2];
    int e = ((unsigned short)v >> 7) & 0xFF;
    cnt += (e >= 100 && e <= 127) ? 1 : 0;
  }
  __shared__ int tot;
  if (threadIdx.x == 0) tot = 0;
  __syncthreads();
  atomicAdd(&tot, cnt);
  __syncthreads();
  if (threadIdx.x == 0) flag[0] = (tot > 1024) ? 1 : 0;  // 1 = bf16 inputs
}

// ---------- small params -> fp32 block (18 vectors of 256) ------------------
struct P18 { const void* p[18]; };
__global__ __launch_bounds__(256) void prep_params(P18 s, const int* flag, float* pb) {
  int bf = *flag;
  int t = threadIdx.x;
#pragma unroll
  for (int v = 0; v < 18; ++v) pb[v * 256 + t] = ldany(s.p[v], t, bf);
}

// ---------- weight prep: fragment-linear layout -----------------------------
// Per 256x256 matrix: fidx = ntile*4096 + kt*512 + l*8 + j  (shorts), where
// lane l=r+16q reads element (n = ntile*16+r, k = kt*32+q*8+j) = W[k][n].
// A wave's B-frag load for (ntile, kt) is then one coalesced 1KB dwordx4.
__global__ __launch_bounds__(256) void prep_gemm_w(
    const void* w0, const void* w1, const void* w2, const void* w3,
    const void* w4, const void* w5, const int* flag, short* wt) {
  int bf = *flag;
  const void* src;
  switch (blockIdx.y) {
    case 0: src = w0; break;
    case 1: src = w1; break;
    case 2: src = w2; break;
    case 3: src = w3; break;
    case 4: src = w4; break;
    default: src = w5; break;
  }
  int idx = blockIdx.x * 256 + threadIdx.x;     // 0..65535
  int ntile = idx >> 12;          // 0..15
  int kt = (idx >> 9) & 7;        // 0..7
  int l = (idx >> 3) & 63;
  int j = idx & 7;
  int r = l & 15, q = l >> 4;
  int n = ntile * 16 + r;
  int k = kt * 32 + q * 8 + j;
  wt[blockIdx.y * 65536 + idx] = f2b(ldany(src, k * 256 + n, bf));
}

// conv_w [cout][cin][3][3] -> fragment-linear per tap:
// cwt[((tap*16 + mt)*8 + kt32)*512 + l*8 + j]: lane l=r+16q holds
// (cout = mt*16+r, cin = kt32*32 + q*8 + j) of tap.
__global__ __launch_bounds__(256) void prep_conv_w(const void* cw, const int* flag,
                                                   short* cwt) {
  int bf = *flag;
  int idx = blockIdx.x * 256 + threadIdx.x;     // 0..589823
  int j = idx & 7;
  int l = (idx >> 3) & 63;
  int kt32 = (idx >> 9) & 7;
  int mt = (idx >> 12) & 15;
  int tap = idx >> 16;
  int r = l & 15, q = l >> 4;
  int n = mt * 16 + r;
  int k = kt32 * 32 + q * 8 + j;
  cwt[idx] = f2b(ldany(cw, (n * 256 + k) * 9 + tap, bf));
}

// ---------- zero the halo of FROWSpad [2][130][130][256] --------------------
__global__ __launch_bounds__(256) void zero_border(short* rowsPad) {
  int id = blockIdx.x;              // 0..1031
  int b = id >= 516;
  int r = id - b * 516;
  int hp, wp;
  if (r < 130)      { hp = 0;       wp = r; }
  else if (r < 260) { hp = 129;     wp = r - 130; }
  else if (r < 388) { hp = r - 259; wp = 0; }
  else              { hp = r - 387; wp = 129; }
  rowsPad[(b * PADR + hp * 130 + wp) * 256 + threadIdx.x] = 0;
}

// ---------- gather: vectorized tiled transpose + mean -----------------------
__global__ __launch_bounds__(256) void gather_chunk(
    const void* m0, const void* m1, const void* m2, const int* flag,
    short* Xc, short* meanc, int sb0) {
  const int bf = *flag;
  const int bx = blockIdx.x;
  const int seg = bx >> 2;
  const int cb = (bx & 3) * 64;
  const int sb = sb0 + seg;
  const int wt = sb & 1, h = (sb >> 1) & 127, b = sb >> 8;
  const int w0 = wt * 64;
  const int lp0 = seg * 64;
  const int t = threadIdx.x;

  __shared__ short tile[3][64][72];   // [m][c][w(+8 pad)], rows 16B-aligned
  const void* srcs[3] = {m0, m1, m2};

  const int lsub = t & 7;             // w chunk: lsub*8 .. +8
#pragma unroll
  for (int pass = 0; pass < 2; ++pass) {
    int c_l = pass * 32 + (t >> 3);
    long long gbase = ((long long)(b * 256 + cb + c_l) * 128 + h) * 128 + w0 + lsub * 8;
#pragma unroll
    for (int m = 0; m < 3; ++m) {
      u16x8 v;
      if (bf) {
        v = *(const u16x8*)((const short*)srcs[m] + gbase);
      } else {
        const float* gp = (const float*)srcs[m] + gbase;
        f32x4 f0 = *(const f32x4*)gp;
        f32x4 f1 = *(const f32x4*)(gp + 4);
#pragma unroll
        for (int k = 0; k < 4; ++k) {
          v[k] = (unsigned short)f2b(f0[k]);
          v[4 + k] = (unsigned short)f2b(f1[k]);
        }
      }
      *(u16x8*)&tile[m][c_l][lsub * 8] = v;
    }
  }
  __syncthreads();

  const int c0 = (t & 7) * 8;
#pragma unroll
  for (int pass = 0; pass < 2; ++pass) {
    int w_l = pass * 32 + (t >> 3);
    float mv[8];
#pragma unroll
    for (int m = 0; m < 3; ++m) {
      u16x8 v;
#pragma unroll
      for (int k = 0; k < 8; ++k) {
        short s = tile[m][c0 + k][w_l];
        v[k] = (unsigned short)s;
        float f = b2f(s);
        mv[k] = (m == 0) ? f : mv[k] + f;
      }
      *(u16x8*)(Xc + (long long)((lp0 + w_l) * 4 + 1 + m) * 256 + cb + c0) = v;
    }
    u16x8 mb;
#pragma unroll
    for (int k = 0; k < 8; ++k)
      mb[k] = (unsigned short)f2b(mv[k] * (1.f / 3.f));
    *(u16x8*)(meanc + (long long)(lp0 + w_l) * 256 + cb + c0) = mb;
  }
}

// ---------- tiled GEMM: out[m*ostride+n] = A[M,256] @ W^T + bias ------------
// BK=64, 4 steps, double-buffered, 1 barrier/step. A tile [128][64] staged
// with conv-style XOR-8 swizzle; 8 B-frags/step direct from L2 (frag-linear).
// XCD-chunk swizzle keeps A-panel sharers on one XCD's L2. (r15 version.)
template <int RELU>
__global__ __launch_bounds__(256, 3) void gemm_tile(
    const short* __restrict__ A, const short* __restrict__ Bf,
    const float* __restrict__ bias, short* __restrict__ out, int ostride) {
  __shared__ short lds[2][8192];     // 16KB per buffer: A tile 128x64
  const int t = threadIdx.x;
  const int l = t & 63, wv = t >> 6;
  const int bid = blockIdx.y * gridDim.x + blockIdx.x;
  const int wg = xcd_swz(bid, gridDim.x * gridDim.y);
  const int n0 = (wg % gridDim.x) * 128;
  const int m0 = (wg / gridDim.x) * 128;
  const int r = l & 15, q = l >> 4;
  const int wm = wv & 1, wn = wv >> 1;

  // wave's B-frag base: ntile0 = n0/16 + wn*4 (c adds 0..3)
  const short* Bw = Bf + (((n0 >> 4) + wn * 4) << 12) + l * 8;

  f32x4 acc[4][4];
#pragma unroll
  for (int a = 0; a < 4; ++a)
#pragma unroll
    for (int c = 0; c < 4; ++c) acc[a][c] = (f32x4){0.f, 0.f, 0.f, 0.f};

  auto stage = [&](int s64, int bufi) {
    const int k0 = s64 * 64;
#pragma unroll
    for (int p = 0; p < 4; ++p) {      // 1024 x 16B slots = 128 rows x 64 k
      int s0 = p * 256 + wv * 64;      // wave-uniform slot base
      int s = s0 + l;
      int row = s >> 3;                // 8 slots (128B) per row
      int cs = (s & 7) ^ (row & 7);    // pre-swizzled k-chunk
      gload_lds16(A + (m0 + row) * 256 + k0 + cs * 8, &lds[bufi][s0 * 8]);
    }
  };

  stage(0, 0);
  __syncthreads();
#pragma unroll
  for (int s64 = 0; s64 < 4; ++s64) {
    const int cur = s64 & 1;
    bf16x8 af[2][4], bfr[2][4];
#pragma unroll
    for (int kh = 0; kh < 2; ++kh) {
      const int kt = s64 * 2 + kh;
#pragma unroll
      for (int c = 0; c < 4; ++c)
        bfr[kh][c] = *(const bf16x8*)(Bw + (c * 8 + kt) * 512);
#pragma unroll
      for (int a = 0; a < 4; ++a) {
        int R = wm * 64 + a * 16 + r;
        int s = (kh * 4 + q) ^ (R & 7);
        af[kh][a] = *(const bf16x8*)(&lds[cur][R * 64 + s * 8]);
      }
    }
    if (s64 < 3) stage(s64 + 1, cur ^ 1);
#pragma unroll
    for (int kh = 0; kh < 2; ++kh)
#pragma unroll
      for (int a = 0; a < 4; ++a)
#pragma unroll
        for (int c = 0; c < 4; ++c)
          acc[a][c] = __builtin_amdgcn_mfma_f32_16x16x32_bf16(
              af[kh][a], bfr[kh][c], acc[a][c], 0, 0, 0);
    if (s64 < 3) __syncthreads();
  }

#pragma unroll
  for (int c = 0; c < 4; ++c) {
    int n = n0 + wn * 64 + c * 16 + r;
    float bs = bias[n];
#pragma unroll
    for (int a = 0; a < 4; ++a)
#pragma unroll
      for (int i = 0; i < 4; ++i) {
        int m = m0 + wm * 64 + a * 16 + q * 4 + i;
        float v = acc[a][c][i] + bs;
        if (RELU) v = fmaxf(v, 0.f);
        out[m * ostride + n] = f2b(v);
      }
  }
}

// ---------- per-pixel GATv2 + residual + layernorm --------------------------
// Lane e (of 16-lane pixel group) owns 16 CONTIGUOUS channels c = e*16..+15,
// all within head e>>2. Head-score reduce = quad_perm butterfly over the
// 4-lane quad; LN reduce = rsum16 over the pixel group. xl raw-bf16 in regs.
__global__ __launch_bounds__(256) void attn_ln(
    const short* __restrict__ XLRc,
    const float* __restrict__ att, const float* __restrict__ bias,
    const float* __restrict__ lng, const float* __restrict__ lnb,
    short* __restrict__ Xc, int pOff, short* rowsPad, int writeFused) {
  const int lane = threadIdx.x & 63;
  const int wv = threadIdx.x >> 6;
  const int e = lane & 15;
  const int lp = blockIdx.x * 16 + wv * 4 + (lane >> 4);
  const int pg = pOff + lp;
  const int c0 = e * 16;

  float av[16];
#pragma unroll
  for (int k = 0; k < 16; ++k) av[k] = att[c0 + k];

  // all xl upfront (raw bf16: 8 independent 16B loads)
  u16x8 xlr[4][2];
#pragma unroll
  for (int j = 0; j < 4; ++j) {
    const short* rb = XLRc + (lp * 4 + j) * 512 + c0;
    xlr[j][0] = *(const u16x8*)rb;
    xlr[j][1] = *(const u16x8*)(rb + 8);
  }

  // per-node xl att-dots (leaky linear part), per-lane partial
  float lpd[4];
#pragma unroll
  for (int j = 0; j < 4; ++j) {
    float a = 0.f;
#pragma unroll
    for (int k = 0; k < 8; ++k) {
      a += asf(((unsigned)xlr[j][0][k]) << 16) * av[k];
      a += asf(((unsigned)xlr[j][1][k]) << 16) * av[8 + k];
    }
    lpd[j] = a;
  }

#pragma unroll
  for (int i = 0; i < 4; ++i) {
    // xr for target node i
    const short* rbi = XLRc + (lp * 4 + i) * 512 + 256 + c0;
    u16x8 xr0 = *(const u16x8*)rbi;
    u16x8 xr1 = *(const u16x8*)(rbi + 8);
    float xrf[16];
#pragma unroll
    for (int k = 0; k < 8; ++k) {
      xrf[k] = asf(((unsigned)xr0[k]) << 16);
      xrf[8 + k] = asf(((unsigned)xr1[k]) << 16);
    }
    float rpd = 0.f;
#pragma unroll
    for (int k = 0; k < 16; ++k) rpd += xrf[k] * av[k];

    float s[4];
#pragma unroll
    for (int j = 0; j < 4; ++j) {
      float acc = 0.f;
#pragma unroll
      for (int k = 0; k < 8; ++k) {
        float t0 = xrf[k] + asf(((unsigned)xlr[j][0][k]) << 16);
        float t1 = xrf[8 + k] + asf(((unsigned)xlr[j][1][k]) << 16);
        acc += __builtin_fabsf(t0) * av[k];
        acc += __builtin_fabsf(t1) * av[8 + k];
      }
      s[j] = rsum4(0.6f * (rpd + lpd[j]) + 0.4f * acc);
    }
    float mx = fmaxf(fmaxf(s[0], s[1]), fmaxf(s[2], s[3]));
    float e0 = __expf(s[0] - mx), e1 = __expf(s[1] - mx);
    float e2 = __expf(s[2] - mx), e3 = __expf(s[3] - mx);
    float inv = __builtin_amdgcn_rcpf(e0 + e1 + e2 + e3);
    float a0 = e0 * inv, a1 = e1 * inv, a2 = e2 * inv, a3 = e3 * inv;

    // combine + bias + residual
    const short* xres = Xc + (lp * 4 + i) * 256 + c0;
    u16x8 rv0 = *(const u16x8*)xres;
    u16x8 rv1 = *(const u16x8*)(xres + 8);
    float y[16], sm = 0.f;
#pragma unroll
    for (int k = 0; k < 8; ++k) {
      float o0 = a0 * asf(((unsigned)xlr[0][0][k]) << 16) +
                 a1 * asf(((unsigned)xlr[1][0][k]) << 16) +
                 a2 * asf(((unsigned)xlr[2][0][k]) << 16) +
                 a3 * asf(((unsigned)xlr[3][0][k]) << 16);
      float o1 = a0 * asf(((unsigned)xlr[0][1][k]) << 16) +
                 a1 * asf(((unsigned)xlr[1][1][k]) << 16) +
                 a2 * asf(((unsigned)xlr[2][1][k]) << 16) +
                 a3 * asf(((unsigned)xlr[3][1][k]) << 16);
      y[k] = o0 + bias[c0 + k] + asf(((unsigned)rv0[k]) << 16);
      y[8 + k] = o1 + bias[c0 + 8 + k] + asf(((unsigned)rv1[k]) << 16);
      sm += y[k] + y[8 + k];
    }
    sm = rsum16(sm);
    float mu = sm * (1.f / 256.f);
    float vs = 0.f;
#pragma unroll
    for (int k = 0; k < 16; ++k) {
      float d = y[k] - mu;
      vs += d * d;
    }
    vs = rsum16(vs);
    float rs = rsqrtf(vs * (1.f / 256.f) + 1e-5f);

    u16x8 ov0, ov1;
#pragma unroll
    for (int k = 0; k < 8; ++k) {
      ov0[k] = (unsigned short)f2b((y[k] - mu) * rs * lng[c0 + k] + lnb[c0 + k]);
      ov1[k] = (unsigned short)f2b((y[8 + k] - mu) * rs * lng[c0 + 8 + k] +
                                   lnb[c0 + 8 + k]);
    }
    *(u16x8*)(Xc + (lp * 4 + i) * 256 + c0) = ov0;
    *(u16x8*)(Xc + (lp * 4 + i) * 256 + c0 + 8) = ov1;
    if (writeFused && i == 0) {
      int w = pg & 127, hh = (pg >> 7) & 127, b = pg >> 14;
      short* rp_ = rowsPad + (b * PADR + (hh + 1) * 130 + (w + 1)) * 256 + c0;
      *(u16x8*)rp_ = ov0;
      *(u16x8*)(rp_ + 8) = ov1;
    }
  }
}

// ---------- conv3x3: row-reuse implicit GEMM + BN + ReLU + residual ---------
// Block = 64 cout x 128 px (panel-fast mapping: wg&3 = cout panel). 12 stages
// of (ty, ktq64), DOUBLE-buffered: prefetch stage s+1 row-chunk into buf^1,
// compute 48 MFMA on buf[cur], ONE barrier per stage. Weights frag-linear
// direct from L2. Residual read from rowsPad (intra-wave line reuse -> L1).
__global__ __launch_bounds__(256, 4) void conv_tile(
    const short* __restrict__ cwtf, const short* __restrict__ rowsPad,
    const float* __restrict__ bnp,
    const int* __restrict__ flag, void* __restrict__ outp) {
  __shared__ short lds[2][8320];      // 2 x (130 rows x 64 k) = 33.3 KB
  const int bf = *flag;
  const int t = threadIdx.x;
  const int l = t & 63, wv = t >> 6;
  const int bid = blockIdx.y * gridDim.x + blockIdx.x;
  const int wg = xcd_swz(bid, gridDim.x * gridDim.y);
  const int panel = wg & 3;           // cout panel (fast -> same XCD per row)
  const int pb = wg >> 2;             // 0..255: (batch, image row)
  const int bb = pb >> 7, h = pb & 127;
  const int m0 = panel * 64;          // cout base
  const int r = l & 15, q = l >> 4;
  const int wm = wv & 1, wn = wv >> 1;
  const int mtb = (m0 >> 4) + wm * 2;

  f32x4 acc[2][4];
#pragma unroll
  for (int a = 0; a < 2; ++a)
#pragma unroll
    for (int c = 0; c < 4; ++c) acc[a][c] = (f32x4){0.f, 0.f, 0.f, 0.f};

  auto stage = [&](int stp, int bufi) {
    const int ty = stp >> 2, ktq = stp & 3;
    const long long rbase =
        ((long long)(bb * PADR + (h + ty) * 130)) * 256 + ktq * 64;
#pragma unroll
    for (int p = 0; p < 4; ++p) {      // rows 0..127 (1024 x 16B slots)
      int s0 = p * 256 + wv * 64;      // wave-uniform slot base
      int s = s0 + l;
      int row = s >> 3;
      int cs = (s & 7) ^ (row & 7);    // pre-swizzled k-chunk
      gload_lds16(rowsPad + rbase + row * 256 + cs * 8, &lds[bufi][s0 * 8]);
    }
    if (wv == 0) {                     // tail rows 128,129 (256 B, reg-staged)
      int row = 128 + (l >> 5);
      int kc = (l >> 2) & 7;
      int w2 = l & 3;
      unsigned v;
      __builtin_memcpy(&v, rowsPad + rbase + row * 256 + kc * 8 + w2 * 2, 4);
      *(unsigned*)&lds[bufi][row * 64 + ((kc ^ (row & 7)) * 8) + w2 * 2] = v;
    }
  };

  stage(0, 0);
  __syncthreads();
  int cur = 0;
  for (int stp = 0; stp < 12; ++stp) {
    const int ty = stp >> 2, ktq = stp & 3;
    if (stp < 11) stage(stp + 1, cur ^ 1);
#pragma unroll
    for (int tx = 0; tx < 3; ++tx) {
      const int tap = ty * 3 + tx;
#pragma unroll
      for (int kh = 0; kh < 2; ++kh) {
        const int kt32 = ktq * 2 + kh;
        bf16x8 af[2], bfr[4];
#pragma unroll
        for (int a = 0; a < 2; ++a)
          af[a] = *(const bf16x8*)(
              cwtf + (((tap * 16 + mtb + a) * 8 + kt32) * 64 + l) * 8);
#pragma unroll
        for (int c = 0; c < 4; ++c) {
          int R = tx + wn * 64 + c * 16 + r;
          int s = (kh * 4 + q) ^ (R & 7);
          bfr[c] = *(const bf16x8*)(&lds[cur][R * 64 + s * 8]);
        }
#pragma unroll
        for (int a = 0; a < 2; ++a)
#pragma unroll
          for (int c = 0; c < 4; ++c)
            acc[a][c] = __builtin_amdgcn_mfma_f32_16x16x32_bf16(
                af[a], bfr[c], acc[a][c], 0, 0, 0);
      }
    }
    if (stp < 11) { __syncthreads(); cur ^= 1; }
  }

#pragma unroll
  for (int a = 0; a < 2; ++a)
#pragma unroll
    for (int i = 0; i < 4; ++i) {
      int m = m0 + wm * 32 + a * 16 + q * 4 + i;   // cout
      float scale = rsqrtf(bnp[768 + m] + 1e-5f) * bnp[m];
      float bmean = bnp[512 + m], bbeta = bnp[256 + m];
      int ib = ((bb * 256 + m) * 128 + h) * 128;
#pragma unroll
      for (int c = 0; c < 4; ++c) {
        int w = wn * 64 + c * 16 + r;
        float v = (acc[a][c][i] - bmean) * scale + bbeta;
        v = fmaxf(v, 0.f);
        int idx = ib + w;
        float res = v + b2f(rowsPad[((long long)(bb * PADR + (h + 1) * 130 +
                                                 (w + 1))) * 256 + m]);
        if (bf) ((short*)outp)[idx] = f2b(res);
        else    ((float*)outp)[idx] = res;
      }
    }
}

extern "C" void kernel_launch(void* const* d_in, const int* in_sizes, int n_in,
                              void* d_out, int out_size, void* d_ws, size_t ws_size,
                              hipStream_t stream) {
  // Adaptive chunking: NCH >= 2 so the per-chunk inter-kernel working set
  // stays L3-resident (NCH=1's ~350 MB thrashes the 256 MB L3).
  const long long baseS = 18033680LL;
  int NCH = 8;
  for (int cand = 2; cand <= 8; cand <<= 1) {
    long long tot = (baseS + (32768LL / cand) * 3072LL) * 2LL;
    if (tot <= (long long)ws_size) { NCH = cand; break; }
  }
  const int CPIX = 32768 / NCH;

  short* ws = (short*)d_ws;
  short* FROWSP = ws;                        // 8,652,800
  short* FIMG   = ws + 8652800;              // 8,388,608 (unused since r17)
  short* WT     = ws + 17041408;             // 393,216
  short* CWT    = ws + 17434624;             // 589,824
  float* PB     = (float*)(ws + 18024448);   // 18x256 fp32 (9,216 shorts)
  int*   FLAG   = (int*)(ws + 18033664);     // 16 shorts
  short* XLRc   = ws + 18033680;             // CPIX*2048
  short* Xc     = XLRc + (long long)CPIX * 2048;  // CPIX*1024
  short* MEANc  = XLRc;                      // alias (dead before proj writes)
  short* H1c    = XLRc + (long long)CPIX * 256;   // alias
  (void)FIMG;

  detect_dtype<<<1, 256, 0, stream>>>(d_in[3], FLAG);

  P18 pp;
  pp.p[0] = d_in[4];   pp.p[1] = d_in[6];   // fn_b1, fn_b2
  pp.p[2] = d_in[8];   pp.p[3] = d_in[10];  // l0_bl, l0_br
  pp.p[4] = d_in[11];  pp.p[5] = d_in[12];  // l0_att, l0_bias
  pp.p[6] = d_in[13];  pp.p[7] = d_in[14];  // ln0_g, ln0_b
  pp.p[8] = d_in[16];  pp.p[9] = d_in[18];  // l1_bl, l1_br
  pp.p[10] = d_in[19]; pp.p[11] = d_in[20]; // l1_att, l1_bias
  pp.p[12] = d_in[21]; pp.p[13] = d_in[22]; // ln1_g, ln1_b
  pp.p[14] = d_in[24]; pp.p[15] = d_in[25]; // bn_g, bn_b
  pp.p[16] = d_in[26]; pp.p[17] = d_in[27]; // bn_m, bn_v
  prep_params<<<1, 256, 0, stream>>>(pp, FLAG, PB);

  prep_gemm_w<<<dim3(256, 6), 256, 0, stream>>>(d_in[3], d_in[5], d_in[7],
                                                d_in[9], d_in[15], d_in[17],
                                                FLAG, WT);
  prep_conv_w<<<2304, 256, 0, stream>>>(d_in[23], FLAG, CWT);
  zero_border<<<1032, 256, 0, stream>>>(FROWSP);

  for (int ci = 0; ci < NCH; ++ci) {
    gather_chunk<<<(CPIX / 64) * 4, 256, 0, stream>>>(d_in[0], d_in[1], d_in[2],
                                                      FLAG, Xc, MEANc,
                                                      ci * (CPIX / 64));
    // fusion MLP: MEANc -> H1c -> Xc node 0
    gemm_tile<1><<<dim3(2, CPIX / 128), 256, 0, stream>>>(
        MEANc, WT + 0 * 65536, PB + 0 * 256, H1c, 256);
    gemm_tile<0><<<dim3(2, CPIX / 128), 256, 0, stream>>>(
        H1c, WT + 1 * 65536, PB + 1 * 256, Xc, 1024);
    for (int lyr = 0; lyr < 2; ++lyr) {
      // fused [Wl|Wr] projection: N=512 (two adjacent frag-linear matrices)
      gemm_tile<0><<<dim3(4, 4 * CPIX / 128), 256, 0, stream>>>(
          Xc, WT + (2 + 2 * lyr) * 65536, PB + (2 + 6 * lyr) * 256, XLRc, 512);
      attn_ln<<<CPIX / 16, 256, 0, stream>>>(
          XLRc, PB + (4 + 6 * lyr) * 256, PB + (5 + 6 * lyr) * 256,
          PB + (6 + 6 * lyr) * 256, PB + (7 + 6 * lyr) * 256, Xc, ci * CPIX,
          FROWSP, lyr);
    }
  }

  conv_tile<<<dim3(256, 4), 256, 0, stream>>>(CWT, FROWSP, PB + 14 * 256,
                                              FLAG, d_out);
}

// Round 12
// 549.511 us; speedup vs baseline: 1.0497x; 1.0497x over previous
//
#include <hip/hip_runtime.h>

// GNNRoIFusion on MI355X (gfx950).
// B=2, H=W=128, C=256, HEADS=4, D=64, M=3, P=32768 pixels.
// Round 19: attn_ln reverted to r17 (r18 lane-remap regressed: +VGPR live
// state, per-i param re-loads). Added T5 s_setprio(1/0) around the MFMA
// clusters in gemm_tile and conv_tile — both are phase-split pipelined
// schedules (3-4 blocks/CU at different phases) where MFMA-wave priority
// keeps the matrix pipe fed. gemm (r15), conv (r14/r17), chunking (r11).

#define Pn 32768
#define PADR 16900  // 130*130 padded rows per batch

typedef __attribute__((ext_vector_type(8))) short bf16x8;
typedef __attribute__((ext_vector_type(4))) float f32x4;
typedef __attribute__((ext_vector_type(4))) unsigned short u16x4;
typedef __attribute__((ext_vector_type(8))) unsigned short u16x8;
typedef __attribute__((ext_vector_type(2))) unsigned int u32x2;

__device__ __forceinline__ float b2f(short s) {
  unsigned u = ((unsigned)(unsigned short)s) << 16;
  float f;
  __builtin_memcpy(&f, &u, 4);
  return f;
}
__device__ __forceinline__ float asf(unsigned u) {
  float f;
  __builtin_memcpy(&f, &u, 4);
  return f;
}
__device__ __forceinline__ short f2b(float f) {
  unsigned u;
  __builtin_memcpy(&u, &f, 4);
  u += 0x7fffu + ((u >> 16) & 1u);   // RNE to bf16
  return (short)(u >> 16);
}
__device__ __forceinline__ float ldany(const void* p, int i, int bf) {
  return bf ? b2f(((const short*)p)[i]) : ((const float*)p)[i];
}
// async global->LDS, 16B per lane; lds base wave-uniform, lane i -> base+16i
__device__ __forceinline__ void gload_lds16(const short* g, short* l) {
  __builtin_amdgcn_global_load_lds(
      (const __attribute__((address_space(1))) unsigned int*)g,
      (__attribute__((address_space(3))) unsigned int*)l, 16, 0, 0);
}

// Bijective XCD-chunk swizzle (m204): hardware round-robins linear block id
// across 8 XCDs; remap so each XCD owns a contiguous chunk of work ids.
__device__ __forceinline__ int xcd_swz(int bid, int nwg) {
  int q = nwg >> 3, r = nwg & 7;
  int x = bid & 7, p = bid >> 3;
  return (x < r ? x * (q + 1) : r * (q + 1) + (x - r) * q) + p;
}

// DPP rotate-add: sum over each aligned 16-lane row (VALU pipe, no LDS).
template <int CTRL>
__device__ __forceinline__ float dpp_add(float v) {
  int s;
  __builtin_memcpy(&s, &v, 4);
  int m = __builtin_amdgcn_update_dpp(0, s, CTRL, 0xF, 0xF, false);
  float f;
  __builtin_memcpy(&f, &m, 4);
  return v + f;
}
__device__ __forceinline__ float rsum16(float v) {
  v = dpp_add<0x121>(v);   // row_ror:1
  v = dpp_add<0x122>(v);   // row_ror:2
  v = dpp_add<0x124>(v);   // row_ror:4
  v = dpp_add<0x128>(v);   // row_ror:8
  return v;
}

// ---------- dtype probe ------------------------------------------------------
__global__ __launch_bounds__(256) void detect_dtype(const void* probe, int* flag) {
  const short* s = (const short*)probe;
  int cnt = 0;
#pragma unroll
  for (int i = 0; i < 8; ++i) {
    short v = s[(threadIdx.x * 8 + i) * 2];
    int e = ((unsigned short)v >> 7) & 0xFF;
    cnt += (e >= 100 && e <= 127) ? 1 : 0;
  }
  __shared__ int tot;
  if (threadIdx.x == 0) tot = 0;
  __syncthreads();
  atomicAdd(&tot, cnt);
  __syncthreads();
  if (threadIdx.x == 0) flag[0] = (tot > 1024) ? 1 : 0;  // 1 = bf16 inputs
}

// ---------- small params -> fp32 block (18 vectors of 256) ------------------
struct P18 { const void* p[18]; };
__global__ __launch_bounds__(256) void prep_params(P18 s, const int* flag, float* pb) {
  int bf = *flag;
  int t = threadIdx.x;
#pragma unroll
  for (int v = 0; v < 18; ++v) pb[v * 256 + t] = ldany(s.p[v], t, bf);
}

// ---------- weight prep: fragment-linear layout -----------------------------
// Per 256x256 matrix: fidx = ntile*4096 + kt*512 + l*8 + j  (shorts), where
// lane l=r+16q reads element (n = ntile*16+r, k = kt*32+q*8+j) = W[k][n].
// A wave's B-frag load for (ntile, kt) is then one coalesced 1KB dwordx4.
__global__ __launch_bounds__(256) void prep_gemm_w(
    const void* w0, const void* w1, const void* w2, const void* w3,
    const void* w4, const void* w5, const int* flag, short* wt) {
  int bf = *flag;
  const void* src;
  switch (blockIdx.y) {
    case 0: src = w0; break;
    case 1: src = w1; break;
    case 2: src = w2; break;
    case 3: src = w3; break;
    case 4: src = w4; break;
    default: src = w5; break;
  }
  int idx = blockIdx.x * 256 + threadIdx.x;     // 0..65535
  int ntile = idx >> 12;          // 0..15
  int kt = (idx >> 9) & 7;        // 0..7
  int l = (idx >> 3) & 63;
  int j = idx & 7;
  int r = l & 15, q = l >> 4;
  int n = ntile * 16 + r;
  int k = kt * 32 + q * 8 + j;
  wt[blockIdx.y * 65536 + idx] = f2b(ldany(src, k * 256 + n, bf));
}

// conv_w [cout][cin][3][3] -> fragment-linear per tap:
// cwt[((tap*16 + mt)*8 + kt32)*512 + l*8 + j]: lane l=r+16q holds
// (cout = mt*16+r, cin = kt32*32 + q*8 + j) of tap.
__global__ __launch_bounds__(256) void prep_conv_w(const void* cw, const int* flag,
                                                   short* cwt) {
  int bf = *flag;
  int idx = blockIdx.x * 256 + threadIdx.x;     // 0..589823
  int j = idx & 7;
  int l = (idx >> 3) & 63;
  int kt32 = (idx >> 9) & 7;
  int mt = (idx >> 12) & 15;
  int tap = idx >> 16;
  int r = l & 15, q = l >> 4;
  int n = mt * 16 + r;
  int k = kt32 * 32 + q * 8 + j;
  cwt[idx] = f2b(ldany(cw, (n * 256 + k) * 9 + tap, bf));
}

// ---------- zero the halo of FROWSpad [2][130][130][256] --------------------
__global__ __launch_bounds__(256) void zero_border(short* rowsPad) {
  int id = blockIdx.x;              // 0..1031
  int b = id >= 516;
  int r = id - b * 516;
  int hp, wp;
  if (r < 130)      { hp = 0;       wp = r; }
  else if (r < 260) { hp = 129;     wp = r - 130; }
  else if (r < 388) { hp = r - 259; wp = 0; }
  else              { hp = r - 387; wp = 129; }
  rowsPad[(b * PADR + hp * 130 + wp) * 256 + threadIdx.x] = 0;
}

// ---------- gather: vectorized tiled transpose + mean -----------------------
__global__ __launch_bounds__(256) void gather_chunk(
    const void* m0, const void* m1, const void* m2, const int* flag,
    short* Xc, short* meanc, int sb0) {
  const int bf = *flag;
  const int bx = blockIdx.x;
  const int seg = bx >> 2;
  const int cb = (bx & 3) * 64;
  const int sb = sb0 + seg;
  const int wt = sb & 1, h = (sb >> 1) & 127, b = sb >> 8;
  const int w0 = wt * 64;
  const int lp0 = seg * 64;
  const int t = threadIdx.x;

  __shared__ short tile[3][64][72];   // [m][c][w(+8 pad)], rows 16B-aligned
  const void* srcs[3] = {m0, m1, m2};

  const int lsub = t & 7;             // w chunk: lsub*8 .. +8
#pragma unroll
  for (int pass = 0; pass < 2; ++pass) {
    int c_l = pass * 32 + (t >> 3);
    long long gbase = ((long long)(b * 256 + cb + c_l) * 128 + h) * 128 + w0 + lsub * 8;
#pragma unroll
    for (int m = 0; m < 3; ++m) {
      u16x8 v;
      if (bf) {
        v = *(const u16x8*)((const short*)srcs[m] + gbase);
      } else {
        const float* gp = (const float*)srcs[m] + gbase;
        f32x4 f0 = *(const f32x4*)gp;
        f32x4 f1 = *(const f32x4*)(gp + 4);
#pragma unroll
        for (int k = 0; k < 4; ++k) {
          v[k] = (unsigned short)f2b(f0[k]);
          v[4 + k] = (unsigned short)f2b(f1[k]);
        }
      }
      *(u16x8*)&tile[m][c_l][lsub * 8] = v;
    }
  }
  __syncthreads();

  const int c0 = (t & 7) * 8;
#pragma unroll
  for (int pass = 0; pass < 2; ++pass) {
    int w_l = pass * 32 + (t >> 3);
    float mv[8];
#pragma unroll
    for (int m = 0; m < 3; ++m) {
      u16x8 v;
#pragma unroll
      for (int k = 0; k < 8; ++k) {
        short s = tile[m][c0 + k][w_l];
        v[k] = (unsigned short)s;
        float f = b2f(s);
        mv[k] = (m == 0) ? f : mv[k] + f;
      }
      *(u16x8*)(Xc + (long long)((lp0 + w_l) * 4 + 1 + m) * 256 + cb + c0) = v;
    }
    u16x8 mb;
#pragma unroll
    for (int k = 0; k < 8; ++k)
      mb[k] = (unsigned short)f2b(mv[k] * (1.f / 3.f));
    *(u16x8*)(meanc + (long long)(lp0 + w_l) * 256 + cb + c0) = mb;
  }
}

// ---------- tiled GEMM: out[m*ostride+n] = A[M,256] @ W^T + bias ------------
// BK=64, 4 steps, double-buffered, 1 barrier/step. A tile [128][64] staged
// with conv-style XOR-8 swizzle; 8 B-frags/step direct from L2 (frag-linear).
// XCD-chunk swizzle keeps A-panel sharers on one XCD's L2. T5 setprio around
// the per-step 32-MFMA cluster.
template <int RELU>
__global__ __launch_bounds__(256, 3) void gemm_tile(
    const short* __restrict__ A, const short* __restrict__ Bf,
    const float* __restrict__ bias, short* __restrict__ out, int ostride) {
  __shared__ short lds[2][8192];     // 16KB per buffer: A tile 128x64
  const int t = threadIdx.x;
  const int l = t & 63, wv = t >> 6;
  const int bid = blockIdx.y * gridDim.x + blockIdx.x;
  const int wg = xcd_swz(bid, gridDim.x * gridDim.y);
  const int n0 = (wg % gridDim.x) * 128;
  const int m0 = (wg / gridDim.x) * 128;
  const int r = l & 15, q = l >> 4;
  const int wm = wv & 1, wn = wv >> 1;

  // wave's B-frag base: ntile0 = n0/16 + wn*4 (c adds 0..3)
  const short* Bw = Bf + (((n0 >> 4) + wn * 4) << 12) + l * 8;

  f32x4 acc[4][4];
#pragma unroll
  for (int a = 0; a < 4; ++a)
#pragma unroll
    for (int c = 0; c < 4; ++c) acc[a][c] = (f32x4){0.f, 0.f, 0.f, 0.f};

  auto stage = [&](int s64, int bufi) {
    const int k0 = s64 * 64;
#pragma unroll
    for (int p = 0; p < 4; ++p) {      // 1024 x 16B slots = 128 rows x 64 k
      int s0 = p * 256 + wv * 64;      // wave-uniform slot base
      int s = s0 + l;
      int row = s >> 3;                // 8 slots (128B) per row
      int cs = (s & 7) ^ (row & 7);    // pre-swizzled k-chunk
      gload_lds16(A + (m0 + row) * 256 + k0 + cs * 8, &lds[bufi][s0 * 8]);
    }
  };

  stage(0, 0);
  __syncthreads();
#pragma unroll
  for (int s64 = 0; s64 < 4; ++s64) {
    const int cur = s64 & 1;
    bf16x8 af[2][4], bfr[2][4];
#pragma unroll
    for (int kh = 0; kh < 2; ++kh) {
      const int kt = s64 * 2 + kh;
#pragma unroll
      for (int c = 0; c < 4; ++c)
        bfr[kh][c] = *(const bf16x8*)(Bw + (c * 8 + kt) * 512);
#pragma unroll
      for (int a = 0; a < 4; ++a) {
        int R = wm * 64 + a * 16 + r;
        int s = (kh * 4 + q) ^ (R & 7);
        af[kh][a] = *(const bf16x8*)(&lds[cur][R * 64 + s * 8]);
      }
    }
    if (s64 < 3) stage(s64 + 1, cur ^ 1);
    __builtin_amdgcn_s_setprio(1);
#pragma unroll
    for (int kh = 0; kh < 2; ++kh)
#pragma unroll
      for (int a = 0; a < 4; ++a)
#pragma unroll
        for (int c = 0; c < 4; ++c)
          acc[a][c] = __builtin_amdgcn_mfma_f32_16x16x32_bf16(
              af[kh][a], bfr[kh][c], acc[a][c], 0, 0, 0);
    __builtin_amdgcn_s_setprio(0);
    if (s64 < 3) __syncthreads();
  }

#pragma unroll
  for (int c = 0; c < 4; ++c) {
    int n = n0 + wn * 64 + c * 16 + r;
    float bs = bias[n];
#pragma unroll
    for (int a = 0; a < 4; ++a)
#pragma unroll
      for (int i = 0; i < 4; ++i) {
        int m = m0 + wm * 64 + a * 16 + q * 4 + i;
        float v = acc[a][c][i] + bs;
        if (RELU) v = fmaxf(v, 0.f);
        out[m * ostride + n] = f2b(v);
      }
  }
}

// ---------- per-pixel GATv2 + residual + layernorm --------------------------
// 4 pixels per wave: lane = p*16 + e; lane covers d = e*4..e*4+3 per head.
// Reductions over the 16-lane pixel group via DPP row_ror adds.
// Fused output goes ONLY to rowsPad (coalesced); no scattered FIMG writes.
__global__ __launch_bounds__(256) void attn_ln(
    const short* __restrict__ XLRc,
    const float* __restrict__ att, const float* __restrict__ bias,
    const float* __restrict__ lng, const float* __restrict__ lnb,
    short* __restrict__ Xc, int pOff, short* rowsPad, int writeFused) {
  const int lane = threadIdx.x & 63;
  const int wv = threadIdx.x >> 6;
  const int e = lane & 15;                       // d-quarter
  const int lp = blockIdx.x * 16 + wv * 4 + (lane >> 4);
  const int pg = pOff + lp;

  float out[4][4][4];    // [i][h][k]
#pragma unroll
  for (int h = 0; h < 4; ++h) {
    float av[4];
#pragma unroll
    for (int k = 0; k < 4; ++k) av[k] = att[h * 64 + e * 4 + k];
    float xlf[4][4], xrf[4][4];
#pragma unroll
    for (int j = 0; j < 4; ++j) {
      const short* rb = XLRc + (lp * 4 + j) * 512 + h * 64 + e * 4;
      u32x2 xl2 = *(const u32x2*)rb;
      u32x2 xr2 = *(const u32x2*)(rb + 256);
      xlf[j][0] = asf(xl2[0] << 16); xlf[j][1] = asf(xl2[0] & 0xffff0000u);
      xlf[j][2] = asf(xl2[1] << 16); xlf[j][3] = asf(xl2[1] & 0xffff0000u);
      xrf[j][0] = asf(xr2[0] << 16); xrf[j][1] = asf(xr2[0] & 0xffff0000u);
      xrf[j][2] = asf(xr2[1] << 16); xrf[j][3] = asf(xr2[1] & 0xffff0000u);
    }
    // per-lane partial dots: leaky(t)=0.6t+0.4|t|, linear part factors
    float rp[4], lp_[4];
#pragma unroll
    for (int j = 0; j < 4; ++j) {
      float r = 0.f, l2 = 0.f;
#pragma unroll
      for (int k = 0; k < 4; ++k) {
        r += xrf[j][k] * av[k];
        l2 += xlf[j][k] * av[k];
      }
      rp[j] = r;
      lp_[j] = l2;
    }
#pragma unroll
    for (int i = 0; i < 4; ++i) {
      float s[4];
#pragma unroll
      for (int j = 0; j < 4; ++j) {
        float acc = 0.f;
#pragma unroll
        for (int k = 0; k < 4; ++k) {
          float t = xrf[i][k] + xlf[j][k];
          acc += __builtin_fabsf(t) * av[k];
        }
        float ap = 0.6f * (rp[i] + lp_[j]) + 0.4f * acc;
        s[j] = rsum16(ap);
      }
      float mx = fmaxf(fmaxf(s[0], s[1]), fmaxf(s[2], s[3]));
      float e0 = __expf(s[0] - mx), e1 = __expf(s[1] - mx);
      float e2 = __expf(s[2] - mx), e3 = __expf(s[3] - mx);
      float inv = __builtin_amdgcn_rcpf(e0 + e1 + e2 + e3);
      float a0 = e0 * inv, a1 = e1 * inv, a2 = e2 * inv, a3 = e3 * inv;
#pragma unroll
      for (int k = 0; k < 4; ++k)
        out[i][h][k] =
            a0 * xlf[0][k] + a1 * xlf[1][k] + a2 * xlf[2][k] + a3 * xlf[3][k];
    }
  }

  float biasf[4][4];
#pragma unroll
  for (int h = 0; h < 4; ++h)
#pragma unroll
    for (int k = 0; k < 4; ++k) biasf[h][k] = bias[h * 64 + e * 4 + k];

#pragma unroll
  for (int i = 0; i < 4; ++i) {
    float y[4][4], sm = 0.f;
#pragma unroll
    for (int h = 0; h < 4; ++h) {
      u32x2 rv2 = *(const u32x2*)(Xc + (lp * 4 + i) * 256 + h * 64 + e * 4);
      float r0 = asf(rv2[0] << 16), r1 = asf(rv2[0] & 0xffff0000u);
      float r2 = asf(rv2[1] << 16), r3 = asf(rv2[1] & 0xffff0000u);
      y[h][0] = out[i][h][0] + biasf[h][0] + r0;
      y[h][1] = out[i][h][1] + biasf[h][1] + r1;
      y[h][2] = out[i][h][2] + biasf[h][2] + r2;
      y[h][3] = out[i][h][3] + biasf[h][3] + r3;
      sm += y[h][0] + y[h][1] + y[h][2] + y[h][3];
    }
    sm = rsum16(sm);
    float mu = sm * (1.f / 256.f);
    float vs = 0.f;
#pragma unroll
    for (int h = 0; h < 4; ++h)
#pragma unroll
      for (int k = 0; k < 4; ++k) {
        float d = y[h][k] - mu;
        vs += d * d;
      }
    vs = rsum16(vs);
    float rs = rsqrtf(vs * (1.f / 256.f) + 1e-5f);
#pragma unroll
    for (int h = 0; h < 4; ++h) {
      float g0 = lng[h * 64 + e * 4 + 0], g1 = lng[h * 64 + e * 4 + 1];
      float g2 = lng[h * 64 + e * 4 + 2], g3 = lng[h * 64 + e * 4 + 3];
      float b0 = lnb[h * 64 + e * 4 + 0], b1 = lnb[h * 64 + e * 4 + 1];
      float b2 = lnb[h * 64 + e * 4 + 2], b3 = lnb[h * 64 + e * 4 + 3];
      u16x4 ov;
      ov[0] = (unsigned short)f2b((y[h][0] - mu) * rs * g0 + b0);
      ov[1] = (unsigned short)f2b((y[h][1] - mu) * rs * g1 + b1);
      ov[2] = (unsigned short)f2b((y[h][2] - mu) * rs * g2 + b2);
      ov[3] = (unsigned short)f2b((y[h][3] - mu) * rs * g3 + b3);
      *(u16x4*)(Xc + (lp * 4 + i) * 256 + h * 64 + e * 4) = ov;
      if (writeFused && i == 0) {
        int w = pg & 127, hh = (pg >> 7) & 127, b = pg >> 14;
        *(u16x4*)(rowsPad + (b * PADR + (hh + 1) * 130 + (w + 1)) * 256 +
                  h * 64 + e * 4) = ov;
      }
    }
  }
}

// ---------- conv3x3: row-reuse implicit GEMM + BN + ReLU + residual ---------
// Block = 64 cout x 128 px (panel-fast mapping: wg&3 = cout panel). 12 stages
// of (ty, ktq64), DOUBLE-buffered: prefetch stage s+1 row-chunk into buf^1,
// compute 48 MFMA on buf[cur], ONE barrier per stage. Weights frag-linear
// direct from L2. Residual read from rowsPad. T5 setprio around MFMA.
__global__ __launch_bounds__(256, 4) void conv_tile(
    const short* __restrict__ cwtf, const short* __restrict__ rowsPad,
    const float* __restrict__ bnp,
    const int* __restrict__ flag, void* __restrict__ outp) {
  __shared__ short lds[2][8320];      // 2 x (130 rows x 64 k) = 33.3 KB
  const int bf = *flag;
  const int t = threadIdx.x;
  const int l = t & 63, wv = t >> 6;
  const int bid = blockIdx.y * gridDim.x + blockIdx.x;
  const int wg = xcd_swz(bid, gridDim.x * gridDim.y);
  const int panel = wg & 3;           // cout panel (fast -> same XCD per row)
  const int pb = wg >> 2;             // 0..255: (batch, image row)
  const int bb = pb >> 7, h = pb & 127;
  const int m0 = panel * 64;          // cout base
  const int r = l & 15, q = l >> 4;
  const int wm = wv & 1, wn = wv >> 1;
  const int mtb = (m0 >> 4) + wm * 2;

  f32x4 acc[2][4];
#pragma unroll
  for (int a = 0; a < 2; ++a)
#pragma unroll
    for (int c = 0; c < 4; ++c) acc[a][c] = (f32x4){0.f, 0.f, 0.f, 0.f};

  auto stage = [&](int stp, int bufi) {
    const int ty = stp >> 2, ktq = stp & 3;
    const long long rbase =
        ((long long)(bb * PADR + (h + ty) * 130)) * 256 + ktq * 64;
#pragma unroll
    for (int p = 0; p < 4; ++p) {      // rows 0..127 (1024 x 16B slots)
      int s0 = p * 256 + wv * 64;      // wave-uniform slot base
      int s = s0 + l;
      int row = s >> 3;
      int cs = (s & 7) ^ (row & 7);    // pre-swizzled k-chunk
      gload_lds16(rowsPad + rbase + row * 256 + cs * 8, &lds[bufi][s0 * 8]);
    }
    if (wv == 0) {                     // tail rows 128,129 (256 B, reg-staged)
      int row = 128 + (l >> 5);
      int kc = (l >> 2) & 7;
      int w2 = l & 3;
      unsigned v;
      __builtin_memcpy(&v, rowsPad + rbase + row * 256 + kc * 8 + w2 * 2, 4);
      *(unsigned*)&lds[bufi][row * 64 + ((kc ^ (row & 7)) * 8) + w2 * 2] = v;
    }
  };

  stage(0, 0);
  __syncthreads();
  int cur = 0;
  for (int stp = 0; stp < 12; ++stp) {
    const int ty = stp >> 2, ktq = stp & 3;
    if (stp < 11) stage(stp + 1, cur ^ 1);
#pragma unroll
    for (int tx = 0; tx < 3; ++tx) {
      const int tap = ty * 3 + tx;
#pragma unroll
      for (int kh = 0; kh < 2; ++kh) {
        const int kt32 = ktq * 2 + kh;
        bf16x8 af[2], bfr[4];
#pragma unroll
        for (int a = 0; a < 2; ++a)
          af[a] = *(const bf16x8*)(
              cwtf + (((tap * 16 + mtb + a) * 8 + kt32) * 64 + l) * 8);
#pragma unroll
        for (int c = 0; c < 4; ++c) {
          int R = tx + wn * 64 + c * 16 + r;
          int s = (kh * 4 + q) ^ (R & 7);
          bfr[c] = *(const bf16x8*)(&lds[cur][R * 64 + s * 8]);
        }
        __builtin_amdgcn_s_setprio(1);
#pragma unroll
        for (int a = 0; a < 2; ++a)
#pragma unroll
          for (int c = 0; c < 4; ++c)
            acc[a][c] = __builtin_amdgcn_mfma_f32_16x16x32_bf16(
                af[a], bfr[c], acc[a][c], 0, 0, 0);
        __builtin_amdgcn_s_setprio(0);
      }
    }
    if (stp < 11) { __syncthreads(); cur ^= 1; }
  }

#pragma unroll
  for (int a = 0; a < 2; ++a)
#pragma unroll
    for (int i = 0; i < 4; ++i) {
      int m = m0 + wm * 32 + a * 16 + q * 4 + i;   // cout
      float scale = rsqrtf(bnp[768 + m] + 1e-5f) * bnp[m];
      float bmean = bnp[512 + m], bbeta = bnp[256 + m];
      int ib = ((bb * 256 + m) * 128 + h) * 128;
#pragma unroll
      for (int c = 0; c < 4; ++c) {
        int w = wn * 64 + c * 16 + r;
        float v = (acc[a][c][i] - bmean) * scale + bbeta;
        v = fmaxf(v, 0.f);
        int idx = ib + w;
        float res = v + b2f(rowsPad[((long long)(bb * PADR + (h + 1) * 130 +
                                                 (w + 1))) * 256 + m]);
        if (bf) ((short*)outp)[idx] = f2b(res);
        else    ((float*)outp)[idx] = res;
      }
    }
}

extern "C" void kernel_launch(void* const* d_in, const int* in_sizes, int n_in,
                              void* d_out, int out_size, void* d_ws, size_t ws_size,
                              hipStream_t stream) {
  // Adaptive chunking: NCH >= 2 so the per-chunk inter-kernel working set
  // stays L3-resident (NCH=1's ~350 MB thrashes the 256 MB L3).
  const long long baseS = 18033680LL;
  int NCH = 8;
  for (int cand = 2; cand <= 8; cand <<= 1) {
    long long tot = (baseS + (32768LL / cand) * 3072LL) * 2LL;
    if (tot <= (long long)ws_size) { NCH = cand; break; }
  }
  const int CPIX = 32768 / NCH;

  short* ws = (short*)d_ws;
  short* FROWSP = ws;                        // 8,652,800
  short* FIMG   = ws + 8652800;              // 8,388,608 (unused since r17)
  short* WT     = ws + 17041408;             // 393,216
  short* CWT    = ws + 17434624;             // 589,824
  float* PB     = (float*)(ws + 18024448);   // 18x256 fp32 (9,216 shorts)
  int*   FLAG   = (int*)(ws + 18033664);     // 16 shorts
  short* XLRc   = ws + 18033680;             // CPIX*2048
  short* Xc     = XLRc + (long long)CPIX * 2048;  // CPIX*1024
  short* MEANc  = XLRc;                      // alias (dead before proj writes)
  short* H1c    = XLRc + (long long)CPIX * 256;   // alias
  (void)FIMG;

  detect_dtype<<<1, 256, 0, stream>>>(d_in[3], FLAG);

  P18 pp;
  pp.p[0] = d_in[4];   pp.p[1] = d_in[6];   // fn_b1, fn_b2
  pp.p[2] = d_in[8];   pp.p[3] = d_in[10];  // l0_bl, l0_br
  pp.p[4] = d_in[11];  pp.p[5] = d_in[12];  // l0_att, l0_bias
  pp.p[6] = d_in[13];  pp.p[7] = d_in[14];  // ln0_g, ln0_b
  pp.p[8] = d_in[16];  pp.p[9] = d_in[18];  // l1_bl, l1_br
  pp.p[10] = d_in[19]; pp.p[11] = d_in[20]; // l1_att, l1_bias
  pp.p[12] = d_in[21]; pp.p[13] = d_in[22]; // ln1_g, ln1_b
  pp.p[14] = d_in[24]; pp.p[15] = d_in[25]; // bn_g, bn_b
  pp.p[16] = d_in[26]; pp.p[17] = d_in[27]; // bn_m, bn_v
  prep_params<<<1, 256, 0, stream>>>(pp, FLAG, PB);

  prep_gemm_w<<<dim3(256, 6), 256, 0, stream>>>(d_in[3], d_in[5], d_in[7],
                                                d_in[9], d_in[15], d_in[17],
                                                FLAG, WT);
  prep_conv_w<<<2304, 256, 0, stream>>>(d_in[23], FLAG, CWT);
  zero_border<<<1032, 256, 0, stream>>>(FROWSP);

  for (int ci = 0; ci < NCH; ++ci) {
    gather_chunk<<<(CPIX / 64) * 4, 256, 0, stream>>>(d_in[0], d_in[1], d_in[2],
                                                      FLAG, Xc, MEANc,
                                                      ci * (CPIX / 64));
    // fusion MLP: MEANc -> H1c -> Xc node 0
    gemm_tile<1><<<dim3(2, CPIX / 128), 256, 0, stream>>>(
        MEANc, WT + 0 * 65536, PB + 0 * 256, H1c, 256);
    gemm_tile<0><<<dim3(2, CPIX / 128), 256, 0, stream>>>(
        H1c, WT + 1 * 65536, PB + 1 * 256, Xc, 1024);
    for (int lyr = 0; lyr < 2; ++lyr) {
      // fused [Wl|Wr] projection: N=512 (two adjacent frag-linear matrices)
      gemm_tile<0><<<dim3(4, 4 * CPIX / 128), 256, 0, stream>>>(
          Xc, WT + (2 + 2 * lyr) * 65536, PB + (2 + 6 * lyr) * 256, XLRc, 512);
      attn_ln<<<CPIX / 16, 256, 0, stream>>>(
          XLRc, PB + (4 + 6 * lyr) * 256, PB + (5 + 6 * lyr) * 256,
          PB + (6 + 6 * lyr) * 256, PB + (7 + 6 * lyr) * 256, Xc, ci * CPIX,
          FROWSP, lyr);
    }
  }

  conv_tile<<<dim3(256, 4), 256, 0, stream>>>(CWT, FROWSP, PB + 14 * 256,
                                              FLAG, d_out);
}

// Round 14
// 508.662 us; speedup vs baseline: 1.1340x; 1.0803x over previous
//
#include <hip/hip_runtime.h>

// GNNRoIFusion on MI355X (gfx950).
// B=2, H=W=128, C=256, HEADS=4, D=64, M=3, P=32768 pixels.
// Round 21 (= r20 resubmit after infra failure): layer-1 dead-code
// elimination. After the 2nd GAT layer only node 0 (fusion) is consumed (by
// conv, via FROWSP). So: (1) attn_ln templated <ONLY0> — layer-1 computes
// target node 0 only (1/4 the scores/combine/LN, xr loads 1/4, no Xc
// writes); (2) layer-1 projection split into Wl (all rows, N=256) + Wr
// (node-0 rows only via astride=1024) — 5/8 the FLOPs/writes of the fused
// N=512 gemm. Identical math for retained outputs. gemm r15+setprio,
// conv r14/r17+setprio, chunking r11.

#define Pn 32768
#define PADR 16900  // 130*130 padded rows per batch

typedef __attribute__((ext_vector_type(8))) short bf16x8;
typedef __attribute__((ext_vector_type(4))) float f32x4;
typedef __attribute__((ext_vector_type(4))) unsigned short u16x4;
typedef __attribute__((ext_vector_type(8))) unsigned short u16x8;
typedef __attribute__((ext_vector_type(2))) unsigned int u32x2;

__device__ __forceinline__ float b2f(short s) {
  unsigned u = ((unsigned)(unsigned short)s) << 16;
  float f;
  __builtin_memcpy(&f, &u, 4);
  return f;
}
__device__ __forceinline__ float asf(unsigned u) {
  float f;
  __builtin_memcpy(&f, &u, 4);
  return f;
}
__device__ __forceinline__ short f2b(float f) {
  unsigned u;
  __builtin_memcpy(&u, &f, 4);
  u += 0x7fffu + ((u >> 16) & 1u);   // RNE to bf16
  return (short)(u >> 16);
}
__device__ __forceinline__ float ldany(const void* p, int i, int bf) {
  return bf ? b2f(((const short*)p)[i]) : ((const float*)p)[i];
}
// async global->LDS, 16B per lane; lds base wave-uniform, lane i -> base+16i
__device__ __forceinline__ void gload_lds16(const short* g, short* l) {
  __builtin_amdgcn_global_load_lds(
      (const __attribute__((address_space(1))) unsigned int*)g,
      (__attribute__((address_space(3))) unsigned int*)l, 16, 0, 0);
}

// Bijective XCD-chunk swizzle (m204): hardware round-robins linear block id
// across 8 XCDs; remap so each XCD owns a contiguous chunk of work ids.
__device__ __forceinline__ int xcd_swz(int bid, int nwg) {
  int q = nwg >> 3, r = nwg & 7;
  int x = bid & 7, p = bid >> 3;
  return (x < r ? x * (q + 1) : r * (q + 1) + (x - r) * q) + p;
}

// DPP rotate-add: sum over each aligned 16-lane row (VALU pipe, no LDS).
template <int CTRL>
__device__ __forceinline__ float dpp_add(float v) {
  int s;
  __builtin_memcpy(&s, &v, 4);
  int m = __builtin_amdgcn_update_dpp(0, s, CTRL, 0xF, 0xF, false);
  float f;
  __builtin_memcpy(&f, &m, 4);
  return v + f;
}
__device__ __forceinline__ float rsum16(float v) {
  v = dpp_add<0x121>(v);   // row_ror:1
  v = dpp_add<0x122>(v);   // row_ror:2
  v = dpp_add<0x124>(v);   // row_ror:4
  v = dpp_add<0x128>(v);   // row_ror:8
  return v;
}

// ---------- dtype probe ------------------------------------------------------
__global__ __launch_bounds__(256) void detect_dtype(const void* probe, int* flag) {
  const short* s = (const short*)probe;
  int cnt = 0;
#pragma unroll
  for (int i = 0; i < 8; ++i) {
    short v = s[(threadIdx.x * 8 + i) * 2];
    int e = ((unsigned short)v >> 7) & 0xFF;
    cnt += (e >= 100 && e <= 127) ? 1 : 0;
  }
  __shared__ int tot;
  if (threadIdx.x == 0) tot = 0;
  __syncthreads();
  atomicAdd(&tot, cnt);
  __syncthreads();
  if (threadIdx.x == 0) flag[0] = (tot > 1024) ? 1 : 0;  // 1 = bf16 inputs
}

// ---------- small params -> fp32 block (18 vectors of 256) ------------------
struct P18 { const void* p[18]; };
__global__ __launch_bounds__(256) void prep_params(P18 s, const int* flag, float* pb) {
  int bf = *flag;
  int t = threadIdx.x;
#pragma unroll
  for (int v = 0; v < 18; ++v) pb[v * 256 + t] = ldany(s.p[v], t, bf);
}

// ---------- weight prep: fragment-linear layout -----------------------------
// Per 256x256 matrix: fidx = ntile*4096 + kt*512 + l*8 + j  (shorts), where
// lane l=r+16q reads element (n = ntile*16+r, k = kt*32+q*8+j) = W[k][n].
// A wave's B-frag load for (ntile, kt) is then one coalesced 1KB dwordx4.
__global__ __launch_bounds__(256) void prep_gemm_w(
    const void* w0, const void* w1, const void* w2, const void* w3,
    const void* w4, const void* w5, const int* flag, short* wt) {
  int bf = *flag;
  const void* src;
  switch (blockIdx.y) {
    case 0: src = w0; break;
    case 1: src = w1; break;
    case 2: src = w2; break;
    case 3: src = w3; break;
    case 4: src = w4; break;
    default: src = w5; break;
  }
  int idx = blockIdx.x * 256 + threadIdx.x;     // 0..65535
  int ntile = idx >> 12;          // 0..15
  int kt = (idx >> 9) & 7;        // 0..7
  int l = (idx >> 3) & 63;
  int j = idx & 7;
  int r = l & 15, q = l >> 4;
  int n = ntile * 16 + r;
  int k = kt * 32 + q * 8 + j;
  wt[blockIdx.y * 65536 + idx] = f2b(ldany(src, k * 256 + n, bf));
}

// conv_w [cout][cin][3][3] -> fragment-linear per tap:
// cwt[((tap*16 + mt)*8 + kt32)*512 + l*8 + j]: lane l=r+16q holds
// (cout = mt*16+r, cin = kt32*32 + q*8 + j) of tap.
__global__ __launch_bounds__(256) void prep_conv_w(const void* cw, const int* flag,
                                                   short* cwt) {
  int bf = *flag;
  int idx = blockIdx.x * 256 + threadIdx.x;     // 0..589823
  int j = idx & 7;
  int l = (idx >> 3) & 63;
  int kt32 = (idx >> 9) & 7;
  int mt = (idx >> 12) & 15;
  int tap = idx >> 16;
  int r = l & 15, q = l >> 4;
  int n = mt * 16 + r;
  int k = kt32 * 32 + q * 8 + j;
  cwt[idx] = f2b(ldany(cw, (n * 256 + k) * 9 + tap, bf));
}

// ---------- zero the halo of FROWSpad [2][130][130][256] --------------------
__global__ __launch_bounds__(256) void zero_border(short* rowsPad) {
  int id = blockIdx.x;              // 0..1031
  int b = id >= 516;
  int r = id - b * 516;
  int hp, wp;
  if (r < 130)      { hp = 0;       wp = r; }
  else if (r < 260) { hp = 129;     wp = r - 130; }
  else if (r < 388) { hp = r - 259; wp = 0; }
  else              { hp = r - 387; wp = 129; }
  rowsPad[(b * PADR + hp * 130 + wp) * 256 + threadIdx.x] = 0;
}

// ---------- gather: vectorized tiled transpose + mean -----------------------
__global__ __launch_bounds__(256) void gather_chunk(
    const void* m0, const void* m1, const void* m2, const int* flag,
    short* Xc, short* meanc, int sb0) {
  const int bf = *flag;
  const int bx = blockIdx.x;
  const int seg = bx >> 2;
  const int cb = (bx & 3) * 64;
  const int sb = sb0 + seg;
  const int wt = sb & 1, h = (sb >> 1) & 127, b = sb >> 8;
  const int w0 = wt * 64;
  const int lp0 = seg * 64;
  const int t = threadIdx.x;

  __shared__ short tile[3][64][72];   // [m][c][w(+8 pad)], rows 16B-aligned
  const void* srcs[3] = {m0, m1, m2};

  const int lsub = t & 7;             // w chunk: lsub*8 .. +8
#pragma unroll
  for (int pass = 0; pass < 2; ++pass) {
    int c_l = pass * 32 + (t >> 3);
    long long gbase = ((long long)(b * 256 + cb + c_l) * 128 + h) * 128 + w0 + lsub * 8;
#pragma unroll
    for (int m = 0; m < 3; ++m) {
      u16x8 v;
      if (bf) {
        v = *(const u16x8*)((const short*)srcs[m] + gbase);
      } else {
        const float* gp = (const float*)srcs[m] + gbase;
        f32x4 f0 = *(const f32x4*)gp;
        f32x4 f1 = *(const f32x4*)(gp + 4);
#pragma unroll
        for (int k = 0; k < 4; ++k) {
          v[k] = (unsigned short)f2b(f0[k]);
          v[4 + k] = (unsigned short)f2b(f1[k]);
        }
      }
      *(u16x8*)&tile[m][c_l][lsub * 8] = v;
    }
  }
  __syncthreads();

  const int c0 = (t & 7) * 8;
#pragma unroll
  for (int pass = 0; pass < 2; ++pass) {
    int w_l = pass * 32 + (t >> 3);
    float mv[8];
#pragma unroll
    for (int m = 0; m < 3; ++m) {
      u16x8 v;
#pragma unroll
      for (int k = 0; k < 8; ++k) {
        short s = tile[m][c0 + k][w_l];
        v[k] = (unsigned short)s;
        float f = b2f(s);
        mv[k] = (m == 0) ? f : mv[k] + f;
      }
      *(u16x8*)(Xc + (long long)((lp0 + w_l) * 4 + 1 + m) * 256 + cb + c0) = v;
    }
    u16x8 mb;
#pragma unroll
    for (int k = 0; k < 8; ++k)
      mb[k] = (unsigned short)f2b(mv[k] * (1.f / 3.f));
    *(u16x8*)(meanc + (long long)(lp0 + w_l) * 256 + cb + c0) = mb;
  }
}

// ---------- tiled GEMM: out[m*ostride+n] = A[M,256] @ W^T + bias ------------
// BK=64, 4 steps, double-buffered, 1 barrier/step. A tile [128][64] staged
// with conv-style XOR-8 swizzle; 8 B-frags/step direct from L2 (frag-linear).
// astride = elements between consecutive A rows (256 normally; 1024 to use
// every 4th row, i.e. node-0 rows of Xc). T5 setprio around MFMA cluster.
template <int RELU>
__global__ __launch_bounds__(256, 3) void gemm_tile(
    const short* __restrict__ A, const short* __restrict__ Bf,
    const float* __restrict__ bias, short* __restrict__ out, int ostride,
    int astride) {
  __shared__ short lds[2][8192];     // 16KB per buffer: A tile 128x64
  const int t = threadIdx.x;
  const int l = t & 63, wv = t >> 6;
  const int bid = blockIdx.y * gridDim.x + blockIdx.x;
  const int wg = xcd_swz(bid, gridDim.x * gridDim.y);
  const int n0 = (wg % gridDim.x) * 128;
  const int m0 = (wg / gridDim.x) * 128;
  const int r = l & 15, q = l >> 4;
  const int wm = wv & 1, wn = wv >> 1;

  // wave's B-frag base: ntile0 = n0/16 + wn*4 (c adds 0..3)
  const short* Bw = Bf + (((n0 >> 4) + wn * 4) << 12) + l * 8;

  f32x4 acc[4][4];
#pragma unroll
  for (int a = 0; a < 4; ++a)
#pragma unroll
    for (int c = 0; c < 4; ++c) acc[a][c] = (f32x4){0.f, 0.f, 0.f, 0.f};

  auto stage = [&](int s64, int bufi) {
    const int k0 = s64 * 64;
#pragma unroll
    for (int p = 0; p < 4; ++p) {      // 1024 x 16B slots = 128 rows x 64 k
      int s0 = p * 256 + wv * 64;      // wave-uniform slot base
      int s = s0 + l;
      int row = s >> 3;                // 8 slots (128B) per row
      int cs = (s & 7) ^ (row & 7);    // pre-swizzled k-chunk
      gload_lds16(A + (long long)(m0 + row) * astride + k0 + cs * 8,
                  &lds[bufi][s0 * 8]);
    }
  };

  stage(0, 0);
  __syncthreads();
#pragma unroll
  for (int s64 = 0; s64 < 4; ++s64) {
    const int cur = s64 & 1;
    bf16x8 af[2][4], bfr[2][4];
#pragma unroll
    for (int kh = 0; kh < 2; ++kh) {
      const int kt = s64 * 2 + kh;
#pragma unroll
      for (int c = 0; c < 4; ++c)
        bfr[kh][c] = *(const bf16x8*)(Bw + (c * 8 + kt) * 512);
#pragma unroll
      for (int a = 0; a < 4; ++a) {
        int R = wm * 64 + a * 16 + r;
        int s = (kh * 4 + q) ^ (R & 7);
        af[kh][a] = *(const bf16x8*)(&lds[cur][R * 64 + s * 8]);
      }
    }
    if (s64 < 3) stage(s64 + 1, cur ^ 1);
    __builtin_amdgcn_s_setprio(1);
#pragma unroll
    for (int kh = 0; kh < 2; ++kh)
#pragma unroll
      for (int a = 0; a < 4; ++a)
#pragma unroll
        for (int c = 0; c < 4; ++c)
          acc[a][c] = __builtin_amdgcn_mfma_f32_16x16x32_bf16(
              af[kh][a], bfr[kh][c], acc[a][c], 0, 0, 0);
    __builtin_amdgcn_s_setprio(0);
    if (s64 < 3) __syncthreads();
  }

#pragma unroll
  for (int c = 0; c < 4; ++c) {
    int n = n0 + wn * 64 + c * 16 + r;
    float bs = bias[n];
#pragma unroll
    for (int a = 0; a < 4; ++a)
#pragma unroll
      for (int i = 0; i < 4; ++i) {
        int m = m0 + wm * 64 + a * 16 + q * 4 + i;
        float v = acc[a][c][i] + bs;
        if (RELU) v = fmaxf(v, 0.f);
        out[(long long)m * ostride + n] = f2b(v);
      }
  }
}

// ---------- per-pixel GATv2 + residual + layernorm --------------------------
// 4 pixels per wave: lane = p*16 + e; lane covers d = e*4..e*4+3 per head.
// Reductions over the 16-lane pixel group via DPP row_ror adds.
// ONLY0=1 (layer 1): compute target node 0 only; write rowsPad only.
// ONLY0=0 (layer 0): all 4 target nodes; write Xc.
template <int ONLY0>
__global__ __launch_bounds__(256) void attn_ln(
    const short* __restrict__ XLRc,
    const float* __restrict__ att, const float* __restrict__ bias,
    const float* __restrict__ lng, const float* __restrict__ lnb,
    short* __restrict__ Xc, int pOff, short* rowsPad) {
  const int lane = threadIdx.x & 63;
  const int wv = threadIdx.x >> 6;
  const int e = lane & 15;                       // d-quarter
  const int lp = blockIdx.x * 16 + wv * 4 + (lane >> 4);
  const int pg = pOff + lp;
  constexpr int NI = ONLY0 ? 1 : 4;

  float out[NI][4][4];    // [i][h][k]
#pragma unroll
  for (int h = 0; h < 4; ++h) {
    float av[4];
#pragma unroll
    for (int k = 0; k < 4; ++k) av[k] = att[h * 64 + e * 4 + k];
    float xlf[4][4], xrf[NI][4];
#pragma unroll
    for (int j = 0; j < 4; ++j) {
      const short* rb = XLRc + (lp * 4 + j) * 512 + h * 64 + e * 4;
      u32x2 xl2 = *(const u32x2*)rb;
      xlf[j][0] = asf(xl2[0] << 16); xlf[j][1] = asf(xl2[0] & 0xffff0000u);
      xlf[j][2] = asf(xl2[1] << 16); xlf[j][3] = asf(xl2[1] & 0xffff0000u);
      if (!ONLY0 || j == 0) {
        u32x2 xr2 = *(const u32x2*)(rb + 256);
        xrf[ONLY0 ? 0 : j][0] = asf(xr2[0] << 16);
        xrf[ONLY0 ? 0 : j][1] = asf(xr2[0] & 0xffff0000u);
        xrf[ONLY0 ? 0 : j][2] = asf(xr2[1] << 16);
        xrf[ONLY0 ? 0 : j][3] = asf(xr2[1] & 0xffff0000u);
      }
    }
    // per-lane partial dots: leaky(t)=0.6t+0.4|t|, linear part factors
    float lp_[4];
#pragma unroll
    for (int j = 0; j < 4; ++j) {
      float l2 = 0.f;
#pragma unroll
      for (int k = 0; k < 4; ++k) l2 += xlf[j][k] * av[k];
      lp_[j] = l2;
    }
#pragma unroll
    for (int i = 0; i < NI; ++i) {
      float rp = 0.f;
#pragma unroll
      for (int k = 0; k < 4; ++k) rp += xrf[i][k] * av[k];
      float s[4];
#pragma unroll
      for (int j = 0; j < 4; ++j) {
        float acc = 0.f;
#pragma unroll
        for (int k = 0; k < 4; ++k) {
          float t = xrf[i][k] + xlf[j][k];
          acc += __builtin_fabsf(t) * av[k];
        }
        float ap = 0.6f * (rp + lp_[j]) + 0.4f * acc;
        s[j] = rsum16(ap);
      }
      float mx = fmaxf(fmaxf(s[0], s[1]), fmaxf(s[2], s[3]));
      float e0 = __expf(s[0] - mx), e1 = __expf(s[1] - mx);
      float e2 = __expf(s[2] - mx), e3 = __expf(s[3] - mx);
      float inv = __builtin_amdgcn_rcpf(e0 + e1 + e2 + e3);
      float a0 = e0 * inv, a1 = e1 * inv, a2 = e2 * inv, a3 = e3 * inv;
#pragma unroll
      for (int k = 0; k < 4; ++k)
        out[i][h][k] =
            a0 * xlf[0][k] + a1 * xlf[1][k] + a2 * xlf[2][k] + a3 * xlf[3][k];
    }
  }

  float biasf[4][4];
#pragma unroll
  for (int h = 0; h < 4; ++h)
#pragma unroll
    for (int k = 0; k < 4; ++k) biasf[h][k] = bias[h * 64 + e * 4 + k];

#pragma unroll
  for (int i = 0; i < NI; ++i) {
    float y[4][4], sm = 0.f;
#pragma unroll
    for (int h = 0; h < 4; ++h) {
      u32x2 rv2 = *(const u32x2*)(Xc + (lp * 4 + i) * 256 + h * 64 + e * 4);
      float r0 = asf(rv2[0] << 16), r1 = asf(rv2[0] & 0xffff0000u);
      float r2 = asf(rv2[1] << 16), r3 = asf(rv2[1] & 0xffff0000u);
      y[h][0] = out[i][h][0] + biasf[h][0] + r0;
      y[h][1] = out[i][h][1] + biasf[h][1] + r1;
      y[h][2] = out[i][h][2] + biasf[h][2] + r2;
      y[h][3] = out[i][h][3] + biasf[h][3] + r3;
      sm += y[h][0] + y[h][1] + y[h][2] + y[h][3];
    }
    sm = rsum16(sm);
    float mu = sm * (1.f / 256.f);
    float vs = 0.f;
#pragma unroll
    for (int h = 0; h < 4; ++h)
#pragma unroll
      for (int k = 0; k < 4; ++k) {
        float d = y[h][k] - mu;
        vs += d * d;
      }
    vs = rsum16(vs);
    float rs = rsqrtf(vs * (1.f / 256.f) + 1e-5f);
#pragma unroll
    for (int h = 0; h < 4; ++h) {
      float g0 = lng[h * 64 + e * 4 + 0], g1 = lng[h * 64 + e * 4 + 1];
      float g2 = lng[h * 64 + e * 4 + 2], g3 = lng[h * 64 + e * 4 + 3];
      float b0 = lnb[h * 64 + e * 4 + 0], b1 = lnb[h * 64 + e * 4 + 1];
      float b2 = lnb[h * 64 + e * 4 + 2], b3 = lnb[h * 64 + e * 4 + 3];
      u16x4 ov;
      ov[0] = (unsigned short)f2b((y[h][0] - mu) * rs * g0 + b0);
      ov[1] = (unsigned short)f2b((y[h][1] - mu) * rs * g1 + b1);
      ov[2] = (unsigned short)f2b((y[h][2] - mu) * rs * g2 + b2);
      ov[3] = (unsigned short)f2b((y[h][3] - mu) * rs * g3 + b3);
      if (ONLY0) {
        int w = pg & 127, hh = (pg >> 7) & 127, b = pg >> 14;
        *(u16x4*)(rowsPad + (b * PADR + (hh + 1) * 130 + (w + 1)) * 256 +
                  h * 64 + e * 4) = ov;
      } else {
        *(u16x4*)(Xc + (lp * 4 + i) * 256 + h * 64 + e * 4) = ov;
      }
    }
  }
}

// ---------- conv3x3: row-reuse implicit GEMM + BN + ReLU + residual ---------
// Block = 64 cout x 128 px (panel-fast mapping: wg&3 = cout panel). 12 stages
// of (ty, ktq64), DOUBLE-buffered: prefetch stage s+1 row-chunk into buf^1,
// compute 48 MFMA on buf[cur], ONE barrier per stage. Weights frag-linear
// direct from L2. Residual read from rowsPad. T5 setprio around MFMA.
__global__ __launch_bounds__(256, 4) void conv_tile(
    const short* __restrict__ cwtf, const short* __restrict__ rowsPad,
    const float* __restrict__ bnp,
    const int* __restrict__ flag, void* __restrict__ outp) {
  __shared__ short lds[2][8320];      // 2 x (130 rows x 64 k) = 33.3 KB
  const int bf = *flag;
  const int t = threadIdx.x;
  const int l = t & 63, wv = t >> 6;
  const int bid = blockIdx.y * gridDim.x + blockIdx.x;
  const int wg = xcd_swz(bid, gridDim.x * gridDim.y);
  const int panel = wg & 3;           // cout panel (fast -> same XCD per row)
  const int pb = wg >> 2;             // 0..255: (batch, image row)
  const int bb = pb >> 7, h = pb & 127;
  const int m0 = panel * 64;          // cout base
  const int r = l & 15, q = l >> 4;
  const int wm = wv & 1, wn = wv >> 1;
  const int mtb = (m0 >> 4) + wm * 2;

  f32x4 acc[2][4];
#pragma unroll
  for (int a = 0; a < 2; ++a)
#pragma unroll
    for (int c = 0; c < 4; ++c) acc[a][c] = (f32x4){0.f, 0.f, 0.f, 0.f};

  auto stage = [&](int stp, int bufi) {
    const int ty = stp >> 2, ktq = stp & 3;
    const long long rbase =
        ((long long)(bb * PADR + (h + ty) * 130)) * 256 + ktq * 64;
#pragma unroll
    for (int p = 0; p < 4; ++p) {      // rows 0..127 (1024 x 16B slots)
      int s0 = p * 256 + wv * 64;      // wave-uniform slot base
      int s = s0 + l;
      int row = s >> 3;
      int cs = (s & 7) ^ (row & 7);    // pre-swizzled k-chunk
      gload_lds16(rowsPad + rbase + row * 256 + cs * 8, &lds[bufi][s0 * 8]);
    }
    if (wv == 0) {                     // tail rows 128,129 (256 B, reg-staged)
      int row = 128 + (l >> 5);
      int kc = (l >> 2) & 7;
      int w2 = l & 3;
      unsigned v;
      __builtin_memcpy(&v, rowsPad + rbase + row * 256 + kc * 8 + w2 * 2, 4);
      *(unsigned*)&lds[bufi][row * 64 + ((kc ^ (row & 7)) * 8) + w2 * 2] = v;
    }
  };

  stage(0, 0);
  __syncthreads();
  int cur = 0;
  for (int stp = 0; stp < 12; ++stp) {
    const int ty = stp >> 2, ktq = stp & 3;
    if (stp < 11) stage(stp + 1, cur ^ 1);
#pragma unroll
    for (int tx = 0; tx < 3; ++tx) {
      const int tap = ty * 3 + tx;
#pragma unroll
      for (int kh = 0; kh < 2; ++kh) {
        const int kt32 = ktq * 2 + kh;
        bf16x8 af[2], bfr[4];
#pragma unroll
        for (int a = 0; a < 2; ++a)
          af[a] = *(const bf16x8*)(
              cwtf + (((tap * 16 + mtb + a) * 8 + kt32) * 64 + l) * 8);
#pragma unroll
        for (int c = 0; c < 4; ++c) {
          int R = tx + wn * 64 + c * 16 + r;
          int s = (kh * 4 + q) ^ (R & 7);
          bfr[c] = *(const bf16x8*)(&lds[cur][R * 64 + s * 8]);
        }
        __builtin_amdgcn_s_setprio(1);
#pragma unroll
        for (int a = 0; a < 2; ++a)
#pragma unroll
          for (int c = 0; c < 4; ++c)
            acc[a][c] = __builtin_amdgcn_mfma_f32_16x16x32_bf16(
                af[a], bfr[c], acc[a][c], 0, 0, 0);
        __builtin_amdgcn_s_setprio(0);
      }
    }
    if (stp < 11) { __syncthreads(); cur ^= 1; }
  }

#pragma unroll
  for (int a = 0; a < 2; ++a)
#pragma unroll
    for (int i = 0; i < 4; ++i) {
      int m = m0 + wm * 32 + a * 16 + q * 4 + i;   // cout
      float scale = rsqrtf(bnp[768 + m] + 1e-5f) * bnp[m];
      float bmean = bnp[512 + m], bbeta = bnp[256 + m];
      int ib = ((bb * 256 + m) * 128 + h) * 128;
#pragma unroll
      for (int c = 0; c < 4; ++c) {
        int w = wn * 64 + c * 16 + r;
        float v = (acc[a][c][i] - bmean) * scale + bbeta;
        v = fmaxf(v, 0.f);
        int idx = ib + w;
        float res = v + b2f(rowsPad[((long long)(bb * PADR + (h + 1) * 130 +
                                                 (w + 1))) * 256 + m]);
        if (bf) ((short*)outp)[idx] = f2b(res);
        else    ((float*)outp)[idx] = res;
      }
    }
}

extern "C" void kernel_launch(void* const* d_in, const int* in_sizes, int n_in,
                              void* d_out, int out_size, void* d_ws, size_t ws_size,
                              hipStream_t stream) {
  // Adaptive chunking: NCH >= 2 so the per-chunk inter-kernel working set
  // stays L3-resident (NCH=1's ~350 MB thrashes the 256 MB L3).
  const long long baseS = 18033680LL;
  int NCH = 8;
  for (int cand = 2; cand <= 8; cand <<= 1) {
    long long tot = (baseS + (32768LL / cand) * 3072LL) * 2LL;
    if (tot <= (long long)ws_size) { NCH = cand; break; }
  }
  const int CPIX = 32768 / NCH;

  short* ws = (short*)d_ws;
  short* FROWSP = ws;                        // 8,652,800
  short* FIMG   = ws + 8652800;              // 8,388,608 (unused since r17)
  short* WT     = ws + 17041408;             // 393,216
  short* CWT    = ws + 17434624;             // 589,824
  float* PB     = (float*)(ws + 18024448);   // 18x256 fp32 (9,216 shorts)
  int*   FLAG   = (int*)(ws + 18033664);     // 16 shorts
  short* XLRc   = ws + 18033680;             // CPIX*2048
  short* Xc     = XLRc + (long long)CPIX * 2048;  // CPIX*1024
  short* MEANc  = XLRc;                      // alias (dead before proj writes)
  short* H1c    = XLRc + (long long)CPIX * 256;   // alias
  (void)FIMG;

  detect_dtype<<<1, 256, 0, stream>>>(d_in[3], FLAG);

  P18 pp;
  pp.p[0] = d_in[4];   pp.p[1] = d_in[6];   // fn_b1, fn_b2
  pp.p[2] = d_in[8];   pp.p[3] = d_in[10];  // l0_bl, l0_br
  pp.p[4] = d_in[11];  pp.p[5] = d_in[12];  // l0_att, l0_bias
  pp.p[6] = d_in[13];  pp.p[7] = d_in[14];  // ln0_g, ln0_b
  pp.p[8] = d_in[16];  pp.p[9] = d_in[18];  // l1_bl, l1_br
  pp.p[10] = d_in[19]; pp.p[11] = d_in[20]; // l1_att, l1_bias
  pp.p[12] = d_in[21]; pp.p[13] = d_in[22]; // ln1_g, ln1_b
  pp.p[14] = d_in[24]; pp.p[15] = d_in[25]; // bn_g, bn_b
  pp.p[16] = d_in[26]; pp.p[17] = d_in[27]; // bn_m, bn_v
  prep_params<<<1, 256, 0, stream>>>(pp, FLAG, PB);

  prep_gemm_w<<<dim3(256, 6), 256, 0, stream>>>(d_in[3], d_in[5], d_in[7],
                                                d_in[9], d_in[15], d_in[17],
                                                FLAG, WT);
  prep_conv_w<<<2304, 256, 0, stream>>>(d_in[23], FLAG, CWT);
  zero_border<<<1032, 256, 0, stream>>>(FROWSP);

  for (int ci = 0; ci < NCH; ++ci) {
    gather_chunk<<<(CPIX / 64) * 4, 256, 0, stream>>>(d_in[0], d_in[1], d_in[2],
                                                      FLAG, Xc, MEANc,
                                                      ci * (CPIX / 64));
    // fusion MLP: MEANc -> H1c -> Xc node 0
    gemm_tile<1><<<dim3(2, CPIX / 128), 256, 0, stream>>>(
        MEANc, WT + 0 * 65536, PB + 0 * 256, H1c, 256, 256);
    gemm_tile<0><<<dim3(2, CPIX / 128), 256, 0, stream>>>(
        H1c, WT + 1 * 65536, PB + 1 * 256, Xc, 1024, 256);

    // layer 0: fused [Wl|Wr] projection (N=512), full 4-node attn
    gemm_tile<0><<<dim3(4, 4 * CPIX / 128), 256, 0, stream>>>(
        Xc, WT + 2 * 65536, PB + 2 * 256, XLRc, 512, 256);
    attn_ln<0><<<CPIX / 16, 256, 0, stream>>>(
        XLRc, PB + 4 * 256, PB + 5 * 256, PB + 6 * 256, PB + 7 * 256, Xc,
        ci * CPIX, FROWSP);

    // layer 1: only node 0 is live downstream.
    // Wl for all 4*CPIX rows (xl sources), N=256:
    gemm_tile<0><<<dim3(2, 4 * CPIX / 128), 256, 0, stream>>>(
        Xc, WT + 4 * 65536, PB + 8 * 256, XLRc, 512, 256);
    // Wr for node-0 rows only (every 4th row of Xc), N=256:
    gemm_tile<0><<<dim3(2, CPIX / 128), 256, 0, stream>>>(
        Xc, WT + 5 * 65536, PB + 9 * 256, XLRc + 256, 2048, 1024);
    attn_ln<1><<<CPIX / 16, 256, 0, stream>>>(
        XLRc, PB + 10 * 256, PB + 11 * 256, PB + 12 * 256, PB + 13 * 256, Xc,
        ci * CPIX, FROWSP);
  }

  conv_tile<<<dim3(256, 4), 256, 0, stream>>>(CWT, FROWSP, PB + 14 * 256,
                                              FLAG, d_out);
}